// Round 1
// baseline (251.441 us; speedup 1.0000x reference)
//
#include <hip/hip_runtime.h>
#include <stdint.h>

#define DIM 768
#define HEADS 12
#define SEQ 196
#define BATCH 64
#define NTOK (BATCH*SEQ)   // 12544
#define QKVLD (3*DIM)      // 2304, row stride of qkv workspace
#define SCALE 0.125f       // 64^-0.5

using short8  = __attribute__((ext_vector_type(8))) short;
using short4v = __attribute__((ext_vector_type(4))) short;
using float4v = __attribute__((ext_vector_type(4))) float;
using ushort4v = __attribute__((ext_vector_type(4))) unsigned short;

static __device__ __forceinline__ unsigned short f2bf(float f) {
  union { float f; unsigned u; } v; v.f = f;
  unsigned u = v.u;
  u += 0x7fffu + ((u >> 16) & 1u);   // RNE
  return (unsigned short)(u >> 16);
}

#if defined(__has_builtin)
#if __has_builtin(__builtin_amdgcn_global_load_lds)
#define HAS_GLL 1
#endif
#endif

// Stage 16B/lane: global (per-lane ptr g) -> LDS (wave-uniform base l, lane*16B apart)
static __device__ __forceinline__ void gll16(const unsigned short* g, unsigned short* l) {
#ifdef HAS_GLL
  __builtin_amdgcn_global_load_lds(
      (const __attribute__((address_space(1))) void*)g,
      (__attribute__((address_space(3))) void*)l, 16, 0, 0);
#else
  const int lane = threadIdx.x & 63;
  *(short8*)(l + lane * 8) = *(const short8*)g;
#endif
}

// raw barrier (no vmcnt drain) with compiler memory-motion fences
static __device__ __forceinline__ void barx() {
  asm volatile("" ::: "memory");
  __builtin_amdgcn_s_barrier();
  asm volatile("" ::: "memory");
}
#define VMW8 asm volatile("s_waitcnt vmcnt(8)" ::: "memory")
#define VMW4 asm volatile("s_waitcnt vmcnt(4)" ::: "memory")
#define VMW0 asm volatile("s_waitcnt vmcnt(0)" ::: "memory")

// ---------------- pre-pass: cast x fp32 -> bf16 ----------------
__global__ __launch_bounds__(256) void cast_x_kernel(const float* __restrict__ in,
                                                     unsigned short* __restrict__ out) {
  int i = blockIdx.x * 256 + threadIdx.x;      // exactly NTOK*DIM/4 threads
  float4 v = ((const float4*)in)[i];
  ushort4v o;
  o.x = f2bf(v.x); o.y = f2bf(v.y); o.z = f2bf(v.z); o.w = f2bf(v.w);
  ((ushort4v*)out)[i] = o;
}

// ---------------- pre-pass: transpose + cast W [R][C] fp32 -> Wt [C][R] bf16 ----------------
__global__ __launch_bounds__(256) void transpose_cast_kernel(const float* __restrict__ in,
                                                             unsigned short* __restrict__ out,
                                                             int R, int C) {
  __shared__ float tile[32][33];
  int c0 = blockIdx.x * 32, r0 = blockIdx.y * 32;
  int tx = threadIdx.x, ty = threadIdx.y;      // (32,8)
  for (int i = 0; i < 32; i += 8)
    tile[ty + i][tx] = in[(size_t)(r0 + ty + i) * C + c0 + tx];
  __syncthreads();
  for (int i = 0; i < 32; i += 8)
    out[(size_t)(c0 + ty + i) * R + r0 + tx] = f2bf(tile[tx][ty + i]);
}

// ---------------- GEMM: C[M][N] = A[M][768] * Bt[N][768]^T ----------------
// 256x256 tile, BK=32, 8 waves (2Mx4N), 4-deep LDS pipeline, counted vmcnt,
// T2 source-side XOR swizzle (slot ^= row&3), setprio around MFMA clusters.
// MODE 0: C^T-register formulation, bf16 out row-major [M][2304] (packed 8B stores)
// MODE 1: fp32 out[m][768] + bias[n]
template <int MODE>
__global__ __launch_bounds__(512, 2) void gemm256_kernel(const unsigned short* __restrict__ A,
                                                         const unsigned short* __restrict__ Bt,
                                                         const float* __restrict__ bias,
                                                         unsigned short* __restrict__ outB,
                                                         float* __restrict__ outF) {
  constexpr int K = 768;
  constexpr int NT = 24;                               // K-tiles of 32
  __shared__ __align__(16) unsigned short Als[4][8192];   // [slot][256 rows][32 cols]
  __shared__ __align__(16) unsigned short Bls[4][8192];
  const int tid = threadIdx.x;
  const int wid = tid >> 6, lane = tid & 63;
  const int s = lane & 15, q = lane >> 4;
  const int wr = wid >> 2, wc = wid & 3;               // 2x4 wave grid, 128x64 per wave
  const int qx8 = ((q ^ (s & 3)) << 3);                // swizzled 16B slot for frag reads

  // XCD-aware bijective swizzle: contiguous id chunk per XCD -> panels L2-resident.
  const int nbx = gridDim.x;
  const int nb = gridDim.x * gridDim.y;
  int id = blockIdx.y * nbx + blockIdx.x;
  {
    int x = id & 7, lid = id >> 3;
    int per = nb >> 3, big = nb & 7;
    id = (x < big) ? x * (per + 1) + lid
                   : big * (per + 1) + (x - big) * per + lid;
  }
  const int m0 = (id / nbx) * 256;
  const int n0 = (id % nbx) * 256;

  float4v acc[8][4];
#pragma unroll
  for (int i = 0; i < 8; i++)
#pragma unroll
    for (int j = 0; j < 4; j++) acc[i][j] = (float4v){0.f, 0.f, 0.f, 0.f};

  // Staging: half-tile = 128 rows x 32 cols = 1024 x 16B chunks; thread t covers
  // chunks t and 512+t (row +128). Linear LDS dest (gll requirement); the SOURCE
  // column-chunk is pre-permuted by the read-side involution slot^=(row&3).
  const int srow = tid >> 2;                           // 0..127
  const int scol8 = (((tid & 3) ^ (srow & 3)) << 3);   // swizzled source 16B chunk
  const unsigned short* gA = A + (size_t)(m0 + srow) * K + scol8;
  const unsigned short* gB = Bt + (size_t)(n0 + srow) * K + scol8;
  unsigned short* lA0 = &Als[0][0] + wid * 512;
  unsigned short* lB0 = &Bls[0][0] + wid * 512;

  auto stageA = [&](int t_) {
    const unsigned short* g = gA + t_ * 32;
    unsigned short* l = lA0 + (t_ & 3) * 8192;
    gll16(g, l);
    gll16(g + 128 * K, l + 4096);
  };
  auto stageB = [&](int t_) {
    const unsigned short* g = gB + t_ * 32;
    unsigned short* l = lB0 + (t_ & 3) * 8192;
    gll16(g, l);
    gll16(g + 128 * K, l + 4096);
  };

  // prologue: stage tiles 0,1,2 (A,B interleaved so tile0's 4 loads are oldest)
  stageA(0); stageB(0); stageA(1); stageB(1); stageA(2); stageB(2);
  VMW8;            // tile 0 landed; tiles 1,2 stay in flight
  barx();

  const int laneA = (wr * 128 + s) * 32 + qx8;   // element offset of frag base
  const int laneB = (wc * 64 + s) * 32 + qx8;

#pragma unroll 1
  for (int t = 0; t < NT; ++t) {
    const int sl = t & 3;
    const unsigned short* As = &Als[0][0] + sl * 8192;
    const unsigned short* Bs = &Bls[0][0] + sl * 8192;
    short8 bfr[4], afr[4];

    // ---- phase 0: mi 0..3 x nj 0..3 ----
#pragma unroll
    for (int nj = 0; nj < 4; ++nj) bfr[nj] = *(const short8*)&Bs[laneB + nj * 512];
#pragma unroll
    for (int mi = 0; mi < 4; ++mi) afr[mi] = *(const short8*)&As[laneA + mi * 512];
    if (t < NT - 3) stageA(t + 3);
    barx();
    __builtin_amdgcn_s_setprio(1);
#pragma unroll
    for (int mi = 0; mi < 4; ++mi)
#pragma unroll
      for (int nj = 0; nj < 4; ++nj) {
        if (MODE == 0)
          acc[mi][nj] = __builtin_amdgcn_mfma_f32_16x16x32_bf16(bfr[nj], afr[mi], acc[mi][nj], 0, 0, 0);
        else
          acc[mi][nj] = __builtin_amdgcn_mfma_f32_16x16x32_bf16(afr[mi], bfr[nj], acc[mi][nj], 0, 0, 0);
      }
    __builtin_amdgcn_s_setprio(0);
    barx();

    // ---- phase 1: mi 4..7 x nj 0..3 (bfr reused) ----
#pragma unroll
    for (int mi = 0; mi < 4; ++mi) afr[mi] = *(const short8*)&As[laneA + (mi + 4) * 512];
    if (t < NT - 3) stageB(t + 3);
    barx();
    __builtin_amdgcn_s_setprio(1);
#pragma unroll
    for (int mi = 0; mi < 4; ++mi)
#pragma unroll
      for (int nj = 0; nj < 4; ++nj) {
        if (MODE == 0)
          acc[mi + 4][nj] = __builtin_amdgcn_mfma_f32_16x16x32_bf16(bfr[nj], afr[mi], acc[mi + 4][nj], 0, 0, 0);
        else
          acc[mi + 4][nj] = __builtin_amdgcn_mfma_f32_16x16x32_bf16(afr[mi], bfr[nj], acc[mi + 4][nj], 0, 0, 0);
      }
    __builtin_amdgcn_s_setprio(0);
    // boundary: next tile (t+1) staged 3 tiles ago -> counted wait, never 0 mid-loop
    if (t < NT - 3)      { VMW8; }
    else if (t == NT - 3){ VMW4; }
    else if (t == NT - 2){ VMW0; }
    barx();
  }

  if (MODE == 0) {
    // lane (s,q) acc[mi][nj][r] = C[m0+wr*128+mi*16+s][n0+wc*64+nj*16+q*4+r]
#pragma unroll
    for (int mi = 0; mi < 8; ++mi) {
      size_t mrow = (size_t)(m0 + wr * 128 + mi * 16 + s) * QKVLD;
#pragma unroll
      for (int nj = 0; nj < 4; ++nj) {
        int n = n0 + wc * 64 + nj * 16 + q * 4;
        ushort4v ov;
        ov.x = f2bf(acc[mi][nj][0]); ov.y = f2bf(acc[mi][nj][1]);
        ov.z = f2bf(acc[mi][nj][2]); ov.w = f2bf(acc[mi][nj][3]);
        *(ushort4v*)&outB[mrow + n] = ov;
      }
    }
  } else {
    // lane (s,q) acc[mi][nj][r] = C[m0+wr*128+mi*16+q*4+r][n0+wc*64+nj*16+s]
#pragma unroll
    for (int mi = 0; mi < 8; ++mi) {
      int mbase = m0 + wr * 128 + mi * 16 + q * 4;
#pragma unroll
      for (int nj = 0; nj < 4; ++nj) {
        int ng = n0 + wc * 64 + nj * 16 + s;
        float bv = bias[ng];
#pragma unroll
        for (int r = 0; r < 4; ++r)
          outF[(size_t)(mbase + r) * 768 + ng] = acc[mi][nj][r] + bv;
      }
    }
  }
}

// ---------------- attention: one block per (b,h), S^T formulation ----------------
// qkv workspace is [NTOK][2304] row-major: token row b*196+n, cols h*64+d (Q),
// 768+h*64+d (K), 1536+h*64+d (V). All fragment reads stay 16B-contiguous.
__global__ __launch_bounds__(256) void attn_kernel(const unsigned short* __restrict__ qkv,
                                                   const float* __restrict__ static_a,
                                                   unsigned short* __restrict__ outA) {
  constexpr int WV = 228;   // stride: 114 dwords == 18 mod 32 -> b64 frag reads conflict-free
  __shared__ __align__(16) unsigned short Vt[64 * WV];   // V^T [d][m], m zero-padded to 224
  const int tid = threadIdx.x, wid = tid >> 6, lane = tid & 63;
  const int s = lane & 15, q = lane >> 4;
  const int bh = blockIdx.x;
  const int b = bh / 12, h = bh % 12;
  const unsigned short* Qb = qkv + (size_t)b * SEQ * QKVLD + h * 64;
  const unsigned short* Kb = Qb + 768;
  const unsigned short* Vb = Qb + 1536;

  // stage V^T: thread covers m = mb*64 + (tid&63), d = d0..d0+15
  {
    const int ms = tid & 63;
    const int d0 = (tid >> 6) * 16;
    for (int mb = 0; mb < 4; ++mb) {
      int m = mb * 64 + ms;
      if (m < 224) {
        if (m < 196) {
          short8 v0 = *(const short8*)&Vb[(size_t)m * QKVLD + d0];
          short8 v1 = *(const short8*)&Vb[(size_t)m * QKVLD + d0 + 8];
          for (int j = 0; j < 8; j++) Vt[(d0 + j) * WV + m] = (unsigned short)v0[j];
          for (int j = 0; j < 8; j++) Vt[(d0 + 8 + j) * WV + m] = (unsigned short)v1[j];
        } else {
          for (int j = 0; j < 16; j++) Vt[(d0 + j) * WV + m] = 0;
        }
      }
    }
  }
  __syncthreads();

  const int pmbase = (s >> 2) * 8 + (s & 3);   // permuted K-row base for A-frag row s

  for (int qt = wid; qt < 13; qt += 4) {
    const int n0 = qt * 16;
    const int nq = n0 + s;
    const int nql = nq > 195 ? 195 : nq;
    short8 qf0 = *(const short8*)&Qb[(size_t)nql * QKVLD + q * 8];
    short8 qf1 = *(const short8*)&Qb[(size_t)nql * QKVLD + 32 + q * 8];

    // S^T tiles: tt = 0..12 (tt = 2t + h4; tile (t=6,h4=1) is entirely m>=196 -> skipped)
    float4v sacc[14];
    for (int tt = 0; tt < 13; tt++) {
      int t = tt >> 1, h4 = tt & 1;
      int m = t * 32 + h4 * 4 + pmbase;
      if (m > 195) m = 195;                       // garbage rows, masked later
      short8 kf0 = *(const short8*)&Kb[(size_t)m * QKVLD + q * 8];
      short8 kf1 = *(const short8*)&Kb[(size_t)m * QKVLD + 32 + q * 8];
      float4v z = (float4v){0.f, 0.f, 0.f, 0.f};
      z = __builtin_amdgcn_mfma_f32_16x16x32_bf16(kf0, qf0, z, 0, 0, 0);
      z = __builtin_amdgcn_mfma_f32_16x16x32_bf16(kf1, qf1, z, 0, 0, 0);
      sacc[tt] = z;
    }
    sacc[13] = (float4v){0.f, 0.f, 0.f, 0.f};

    // column softmax: lane owns column n. Valid m: tt<12 all; tt==12 only q==0.
    float mx = -3.0e38f;
    for (int tt = 0; tt < 12; tt++)
      for (int i = 0; i < 4; i++) mx = fmaxf(mx, sacc[tt][i]);
    if (q == 0)
      for (int i = 0; i < 4; i++) mx = fmaxf(mx, sacc[12][i]);
    mx = fmaxf(mx, __shfl_xor(mx, 16));
    mx = fmaxf(mx, __shfl_xor(mx, 32));
    const float CE = SCALE * 1.44269504f;
    float sm = 0.f;
    for (int tt = 0; tt < 12; tt++)
      for (int i = 0; i < 4; i++) {
        float e = __builtin_amdgcn_exp2f((sacc[tt][i] - mx) * CE);
        sacc[tt][i] = e; sm += e;
      }
    if (q == 0) {
      for (int i = 0; i < 4; i++) {
        float e = __builtin_amdgcn_exp2f((sacc[12][i] - mx) * CE);
        sacc[12][i] = e; sm += e;
      }
    } else {
      sacc[12] = (float4v){0.f, 0.f, 0.f, 0.f};
    }
    sm += __shfl_xor(sm, 16);
    sm += __shfl_xor(sm, 32);
    const float inv = 1.0f / sm;

    // P^T fragments: pfrag[t][j] = P^T[m = t*32 + q*8 + j][n], j = h4*4 + i
    const float* sa = static_a + ((size_t)h * SEQ + nql) * SEQ;
    short8 pfrag[7];
    for (int t = 0; t < 7; t++) {
      short8 pf;
      for (int h4 = 0; h4 < 2; h4++) {
        int tt = 2 * t + h4;
        bool valid = (tt < 12) || (tt == 12 && q == 0);
        float4v a4 = (float4v){0.f, 0.f, 0.f, 0.f};
        if (valid) a4 = *(const float4v*)(sa + t * 32 + q * 8 + h4 * 4);
        int src = valid ? tt : 13;
        for (int i = 0; i < 4; i++) {
          float pv = valid ? (sacc[src][i] * inv + a4[i]) : 0.f;
          pf[h4 * 4 + i] = (short)f2bf(pv);
        }
      }
      pfrag[t] = pf;
    }

    // O^T = V^T . P^T : A-frag = V^T rows (from LDS, two b64 reads), B-frag = pfrag
    for (int dt = 0; dt < 4; dt++) {
      float4v o = (float4v){0.f, 0.f, 0.f, 0.f};
      for (int t = 0; t < 7; t++) {
        const unsigned short* vp = &Vt[(dt * 16 + s) * WV + t * 32 + q * 8];
        short4v v0 = *(const short4v*)vp;
        short4v v1 = *(const short4v*)(vp + 4);
        short8 vf;
        vf[0] = v0[0]; vf[1] = v0[1]; vf[2] = v0[2]; vf[3] = v0[3];
        vf[4] = v1[0]; vf[5] = v1[1]; vf[6] = v1[2]; vf[7] = v1[3];
        o = __builtin_amdgcn_mfma_f32_16x16x32_bf16(vf, pfrag[t], o, 0, 0, 0);
      }
      // lane holds O^T[d = dt*16 + q*4 + r][n = nq]
      if (nq < 196) {
        ushort4v ov;
        ov.x = f2bf(o[0]); ov.y = f2bf(o[1]); ov.z = f2bf(o[2]); ov.w = f2bf(o[3]);
        *(ushort4v*)&outA[((size_t)b * SEQ + nq) * DIM + h * 64 + dt * 16 + q * 4] = ov;
      }
    }
  }
}

extern "C" void kernel_launch(void* const* d_in, const int* in_sizes, int n_in,
                              void* d_out, int out_size, void* d_ws, size_t ws_size,
                              hipStream_t stream) {
  const float* x        = (const float*)d_in[0];
  const float* Wqkv     = (const float*)d_in[1];
  const float* static_a = (const float*)d_in[2];
  const float* Wproj    = (const float*)d_in[3];
  const float* bproj    = (const float*)d_in[4];
  float* out = (float*)d_out;

  unsigned char* ws = (unsigned char*)d_ws;
  size_t off = 0;
  unsigned short* qkv_ws = (unsigned short*)(ws + off); off += (size_t)NTOK * QKVLD * 2;   // 57.8 MB
  unsigned short* xa_ws  = (unsigned short*)(ws + off); off += (size_t)NTOK * DIM * 2;     // x_bf16, reused as attn-out
  unsigned short* wqkvt  = (unsigned short*)(ws + off); off += (size_t)3 * DIM * DIM * 2;  // W_qkv^T bf16
  unsigned short* wprojt = (unsigned short*)(ws + off); off += (size_t)DIM * DIM * 2;      // W_proj^T bf16

  cast_x_kernel<<<NTOK * DIM / 4 / 256, 256, 0, stream>>>(x, xa_ws);
  transpose_cast_kernel<<<dim3(3 * DIM / 32, DIM / 32), dim3(32, 8), 0, stream>>>(Wqkv, wqkvt, DIM, 3 * DIM);
  transpose_cast_kernel<<<dim3(DIM / 32, DIM / 32), dim3(32, 8), 0, stream>>>(Wproj, wprojt, DIM, DIM);
  gemm256_kernel<0><<<dim3(3 * DIM / 256, NTOK / 256), 512, 0, stream>>>(xa_ws, wqkvt, nullptr, qkv_ws, nullptr);
  attn_kernel<<<BATCH * HEADS, 256, 0, stream>>>(qkv_ws, static_a, xa_ws);
  gemm256_kernel<1><<<dim3(DIM / 256, NTOK / 256), 512, 0, stream>>>(xa_ws, wprojt, bproj, nullptr, out);
}

// Round 2
// 242.729 us; speedup vs baseline: 1.0359x; 1.0359x over previous
//
#include <hip/hip_runtime.h>
#include <stdint.h>

#define DIM 768
#define HEADS 12
#define SEQ 196
#define BATCH 64
#define NTOK (BATCH*SEQ)   // 12544
#define QKVLD (3*DIM)      // 2304, row stride of qkv workspace
#define SCALE 0.125f       // 64^-0.5

using short8  = __attribute__((ext_vector_type(8))) short;
using short4v = __attribute__((ext_vector_type(4))) short;
using float4v = __attribute__((ext_vector_type(4))) float;
using ushort4v = __attribute__((ext_vector_type(4))) unsigned short;

static __device__ __forceinline__ unsigned short f2bf(float f) {
  union { float f; unsigned u; } v; v.f = f;
  unsigned u = v.u;
  u += 0x7fffu + ((u >> 16) & 1u);   // RNE
  return (unsigned short)(u >> 16);
}

#if defined(__has_builtin)
#if __has_builtin(__builtin_amdgcn_global_load_lds)
#define HAS_GLL 1
#endif
#endif

// Stage 16B/lane: global (per-lane ptr g) -> LDS (wave-uniform base l, lane*16B apart)
static __device__ __forceinline__ void gll16(const unsigned short* g, unsigned short* l) {
#ifdef HAS_GLL
  __builtin_amdgcn_global_load_lds(
      (const __attribute__((address_space(1))) void*)g,
      (__attribute__((address_space(3))) void*)l, 16, 0, 0);
#else
  const int lane = threadIdx.x & 63;
  *(short8*)(l + lane * 8) = *(const short8*)g;
#endif
}

// raw barrier (no vmcnt drain) with compiler memory-motion fences
static __device__ __forceinline__ void barx() {
  asm volatile("" ::: "memory");
  __builtin_amdgcn_s_barrier();
  asm volatile("" ::: "memory");
}
#define VMW8 asm volatile("s_waitcnt vmcnt(8)" ::: "memory")
#define VMW4 asm volatile("s_waitcnt vmcnt(4)" ::: "memory")
#define VMW0 asm volatile("s_waitcnt vmcnt(0)" ::: "memory")

// ---------------- pre-pass: cast x fp32 -> bf16 ----------------
__global__ __launch_bounds__(256) void cast_x_kernel(const float* __restrict__ in,
                                                     unsigned short* __restrict__ out) {
  int i = blockIdx.x * 256 + threadIdx.x;      // exactly NTOK*DIM/4 threads
  float4 v = ((const float4*)in)[i];
  ushort4v o;
  o.x = f2bf(v.x); o.y = f2bf(v.y); o.z = f2bf(v.z); o.w = f2bf(v.w);
  ((ushort4v*)out)[i] = o;
}

// ---------------- pre-pass: transpose + cast W [R][C] fp32 -> Wt [C][R] bf16 ----------------
__global__ __launch_bounds__(256) void transpose_cast_kernel(const float* __restrict__ in,
                                                             unsigned short* __restrict__ out,
                                                             int R, int C) {
  __shared__ float tile[32][33];
  int c0 = blockIdx.x * 32, r0 = blockIdx.y * 32;
  int tx = threadIdx.x, ty = threadIdx.y;      // (32,8)
  for (int i = 0; i < 32; i += 8)
    tile[ty + i][tx] = in[(size_t)(r0 + ty + i) * C + c0 + tx];
  __syncthreads();
  for (int i = 0; i < 32; i += 8)
    out[(size_t)(c0 + ty + i) * R + r0 + tx] = f2bf(tile[tx][ty + i]);
}

// ---------------- pre-pass: transpose static_a per head: saT[h][m][n] = sa[h][n][m] ----------------
__global__ __launch_bounds__(256) void transpose_sa_kernel(const float* __restrict__ in,
                                                           float* __restrict__ out) {
  __shared__ float tile[32][33];
  const int h = blockIdx.z;
  const int n0 = blockIdx.x * 32, m0 = blockIdx.y * 32;
  const int tx = threadIdx.x, ty = threadIdx.y;   // (32,8)
  const float* inh = in + (size_t)h * SEQ * SEQ;
  float* outh = out + (size_t)h * SEQ * SEQ;
  for (int i = 0; i < 32; i += 8)
    if (n0 + ty + i < SEQ && m0 + tx < SEQ)
      tile[ty + i][tx] = inh[(size_t)(n0 + ty + i) * SEQ + m0 + tx];
  __syncthreads();
  for (int i = 0; i < 32; i += 8)
    if (m0 + ty + i < SEQ && n0 + tx < SEQ)
      outh[(size_t)(m0 + ty + i) * SEQ + n0 + tx] = tile[tx][ty + i];
}

// ---------------- GEMM: C[M][N] = A[M][768] * Bt[N][768]^T ----------------
// 256x256 tile, BK=32, 8 waves (2Mx4N), 4-deep LDS pipeline, counted vmcnt.
// ONE barrier per K-tile: waves free-run within a tile so LDS reads of one wave
// overlap MFMA of another (LDS pipe ~1150 cyc/tile/CU vs MFMA ~1240 -> must overlap).
// Swizzle: chunk ^= (row>>1)&3 -> conflict-free within each 16-lane quarter
// (bank period = 128B = 2 rows; q^( (s>>1)&3 ) spreads 16 lanes 2-per-granule).
// MODE 0: C^T-register formulation, bf16 out row-major [M][2304]
// MODE 1: fp32 out[m][768] + bias[n]
template <int MODE>
__global__ __launch_bounds__(512, 2) void gemm256_kernel(const unsigned short* __restrict__ A,
                                                         const unsigned short* __restrict__ Bt,
                                                         const float* __restrict__ bias,
                                                         unsigned short* __restrict__ outB,
                                                         float* __restrict__ outF) {
  constexpr int K = 768;
  constexpr int NT = 24;                               // K-tiles of 32
  __shared__ __align__(16) unsigned short Als[4][8192];   // [slot][256 rows][32 cols]
  __shared__ __align__(16) unsigned short Bls[4][8192];
  const int tid = threadIdx.x;
  const int wid = tid >> 6, lane = tid & 63;
  const int s = lane & 15, q = lane >> 4;
  const int wr = wid >> 2, wc = wid & 3;               // 2x4 wave grid, 128x64 per wave
  const int qx8 = ((q ^ ((s >> 1) & 3)) << 3);         // swizzled 16B slot for frag reads

  // XCD-aware bijective swizzle: contiguous id chunk per XCD -> panels L2-resident.
  const int nbx = gridDim.x;
  const int nb = gridDim.x * gridDim.y;
  int id = blockIdx.y * nbx + blockIdx.x;
  {
    int x = id & 7, lid = id >> 3;
    int per = nb >> 3, big = nb & 7;
    id = (x < big) ? x * (per + 1) + lid
                   : big * (per + 1) + (x - big) * per + lid;
  }
  const int m0 = (id / nbx) * 256;
  const int n0 = (id % nbx) * 256;

  float4v acc[8][4];
#pragma unroll
  for (int i = 0; i < 8; i++)
#pragma unroll
    for (int j = 0; j < 4; j++) acc[i][j] = (float4v){0.f, 0.f, 0.f, 0.f};

  // Staging: thread t covers 16B chunks t and 512+t (row +128). Linear LDS dest
  // (gll requirement); SOURCE column-chunk pre-permuted by the read involution.
  const int srow = tid >> 2;                             // 0..127
  const int scol8 = (((tid & 3) ^ ((srow >> 1) & 3)) << 3);
  const unsigned short* gA = A + (size_t)(m0 + srow) * K + scol8;
  const unsigned short* gB = Bt + (size_t)(n0 + srow) * K + scol8;
  unsigned short* lA0 = &Als[0][0] + wid * 512;
  unsigned short* lB0 = &Bls[0][0] + wid * 512;

  auto stage = [&](int t_) {
    const unsigned short* a = gA + t_ * 32;
    const unsigned short* b = gB + t_ * 32;
    unsigned short* la = lA0 + (t_ & 3) * 8192;
    unsigned short* lb = lB0 + (t_ & 3) * 8192;
    gll16(a, la); gll16(a + 128 * K, la + 4096);
    gll16(b, lb); gll16(b + 128 * K, lb + 4096);
  };

  // prologue: stage tiles 0,1,2
  stage(0); stage(1); stage(2);
  VMW8;            // tile 0 landed (12 outstanding -> 8); tiles 1,2 in flight
  barx();

  const int laneA = (wr * 128 + s) * 32 + qx8;   // element offset of frag base
  const int laneB = (wc * 64 + s) * 32 + qx8;

#pragma unroll 1
  for (int t = 0; t < NT; ++t) {
    const unsigned short* As = &Als[0][0] + (t & 3) * 8192;
    const unsigned short* Bs = &Bls[0][0] + (t & 3) * 8192;
    short8 bfr[4], afr[4], afr2[4];
#pragma unroll
    for (int nj = 0; nj < 4; ++nj) bfr[nj] = *(const short8*)&Bs[laneB + nj * 512];
#pragma unroll
    for (int mi = 0; mi < 4; ++mi) afr[mi]  = *(const short8*)&As[laneA + mi * 512];
#pragma unroll
    for (int mi = 0; mi < 4; ++mi) afr2[mi] = *(const short8*)&As[laneA + (mi + 4) * 512];
    if (t < NT - 3) stage(t + 3);
    __builtin_amdgcn_s_setprio(1);
#pragma unroll
    for (int mi = 0; mi < 4; ++mi)
#pragma unroll
      for (int nj = 0; nj < 4; ++nj) {
        if (MODE == 0)
          acc[mi][nj] = __builtin_amdgcn_mfma_f32_16x16x32_bf16(bfr[nj], afr[mi], acc[mi][nj], 0, 0, 0);
        else
          acc[mi][nj] = __builtin_amdgcn_mfma_f32_16x16x32_bf16(afr[mi], bfr[nj], acc[mi][nj], 0, 0, 0);
      }
#pragma unroll
    for (int mi = 0; mi < 4; ++mi)
#pragma unroll
      for (int nj = 0; nj < 4; ++nj) {
        if (MODE == 0)
          acc[mi + 4][nj] = __builtin_amdgcn_mfma_f32_16x16x32_bf16(bfr[nj], afr2[mi], acc[mi + 4][nj], 0, 0, 0);
        else
          acc[mi + 4][nj] = __builtin_amdgcn_mfma_f32_16x16x32_bf16(afr2[mi], bfr[nj], acc[mi + 4][nj], 0, 0, 0);
      }
    __builtin_amdgcn_s_setprio(0);
    // counted wait: tile t+1's 4 loads (issued at t-2) drained; t+2,t+3 in flight
    if (t < NT - 3)      { VMW8; }
    else if (t == NT - 3){ VMW4; }
    else if (t == NT - 2){ VMW0; }
    barx();
  }

  if (MODE == 0) {
    // lane (s,q) acc[mi][nj][r] = C[m0+wr*128+mi*16+s][n0+wc*64+nj*16+q*4+r]
#pragma unroll
    for (int mi = 0; mi < 8; ++mi) {
      size_t mrow = (size_t)(m0 + wr * 128 + mi * 16 + s) * QKVLD;
#pragma unroll
      for (int nj = 0; nj < 4; ++nj) {
        int n = n0 + wc * 64 + nj * 16 + q * 4;
        ushort4v ov;
        ov.x = f2bf(acc[mi][nj][0]); ov.y = f2bf(acc[mi][nj][1]);
        ov.z = f2bf(acc[mi][nj][2]); ov.w = f2bf(acc[mi][nj][3]);
        *(ushort4v*)&outB[mrow + n] = ov;
      }
    }
  } else {
    // lane (s,q) acc[mi][nj][r] = C[m0+wr*128+mi*16+q*4+r][n0+wc*64+nj*16+s]
#pragma unroll
    for (int mi = 0; mi < 8; ++mi) {
      int mbase = m0 + wr * 128 + mi * 16 + q * 4;
#pragma unroll
      for (int nj = 0; nj < 4; ++nj) {
        int ng = n0 + wc * 64 + nj * 16 + s;
        float bv = bias[ng];
#pragma unroll
        for (int r = 0; r < 4; ++r)
          outF[(size_t)(mbase + r) * 768 + ng] = acc[mi][nj][r] + bv;
      }
    }
  }
}

// ---------------- attention: one block per (b,h), S^T formulation ----------------
// qkv workspace is [NTOK][2304] row-major. K is staged into LDS once (coalesced
// 128B global reads), XOR-swizzled so the permuted-row fragment reads are
// conflict-free-ish; static_a is pre-transposed so bias loads are lane-coalesced.
__global__ __launch_bounds__(256) void attn_kernel(const unsigned short* __restrict__ qkv,
                                                   const float* __restrict__ saT,
                                                   unsigned short* __restrict__ outA) {
  constexpr int WV = 228;   // stride: 114 dwords == 18 mod 32 -> b64 frag reads conflict-free
  __shared__ __align__(16) unsigned short Kl[196 * 64];  // K rows, chunk-swizzled
  __shared__ __align__(16) unsigned short Vt[64 * WV];   // V^T [d][m], m zero-padded to 224
  const int tid = threadIdx.x, wid = tid >> 6, lane = tid & 63;
  const int s = lane & 15, q = lane >> 4;
  const int bh = blockIdx.x;
  const int b = bh / 12, h = bh % 12;
  const unsigned short* Qb = qkv + (size_t)b * SEQ * QKVLD + h * 64;
  const unsigned short* Kb = Qb + 768;
  const unsigned short* Vb = Qb + 1536;

  // stage K: row r, chunk c (16B); LDS chunk = c ^ gK(r); 8 lanes/row -> 128B coalesced
  {
    const int r0 = tid >> 3, c = tid & 7;
    for (int p = 0; p < 7; ++p) {
      int r = p * 32 + r0;
      if (r < 196) {
        short8 v = *(const short8*)&Kb[(size_t)r * QKVLD + c * 8];
        int gk = ((r >> 3) & 3) ^ ((r & 1) << 2);
        *(short8*)&Kl[r * 64 + ((c ^ gk) << 3)] = v;
      }
    }
  }
  // stage V^T: thread covers m = mb*64 + (tid&63), d = d0..d0+15
  {
    const int ms = tid & 63;
    const int d0 = (tid >> 6) * 16;
    for (int mb = 0; mb < 4; ++mb) {
      int m = mb * 64 + ms;
      if (m < 224) {
        if (m < 196) {
          short8 v0 = *(const short8*)&Vb[(size_t)m * QKVLD + d0];
          short8 v1 = *(const short8*)&Vb[(size_t)m * QKVLD + d0 + 8];
          for (int j = 0; j < 8; j++) Vt[(d0 + j) * WV + m] = (unsigned short)v0[j];
          for (int j = 0; j < 8; j++) Vt[(d0 + 8 + j) * WV + m] = (unsigned short)v1[j];
        } else {
          for (int j = 0; j < 16; j++) Vt[(d0 + j) * WV + m] = 0;
        }
      }
    }
  }
  __syncthreads();

  const int pmbase = (s >> 2) * 8 + (s & 3);   // permuted K-row base for A-frag row s
  const float* saTh = saT + (size_t)h * SEQ * SEQ;

  for (int qt = wid; qt < 13; qt += 4) {
    const int n0 = qt * 16;
    const int nq = n0 + s;
    const int nql = nq > 195 ? 195 : nq;
    short8 qf0 = *(const short8*)&Qb[(size_t)nql * QKVLD + q * 8];
    short8 qf1 = *(const short8*)&Qb[(size_t)nql * QKVLD + 32 + q * 8];

    // S^T tiles: tt = 0..12 (tt = 2t + h4; tile (t=6,h4=1) is entirely m>=196 -> skipped)
    float4v sacc[14];
    for (int tt = 0; tt < 13; tt++) {
      int t = tt >> 1, h4 = tt & 1;
      int m = t * 32 + h4 * 4 + pmbase;
      if (m > 195) m = 195;                       // garbage rows, masked later
      int gk = ((m >> 3) & 3) ^ ((m & 1) << 2);
      short8 kf0 = *(const short8*)&Kl[m * 64 + ((q ^ gk) << 3)];
      short8 kf1 = *(const short8*)&Kl[m * 64 + (((4 + q) ^ gk) << 3)];
      float4v z = (float4v){0.f, 0.f, 0.f, 0.f};
      z = __builtin_amdgcn_mfma_f32_16x16x32_bf16(kf0, qf0, z, 0, 0, 0);
      z = __builtin_amdgcn_mfma_f32_16x16x32_bf16(kf1, qf1, z, 0, 0, 0);
      sacc[tt] = z;
    }
    sacc[13] = (float4v){0.f, 0.f, 0.f, 0.f};

    // column softmax: lane owns column n. Valid m: tt<12 all; tt==12 only q==0.
    float mx = -3.0e38f;
    for (int tt = 0; tt < 12; tt++)
      for (int i = 0; i < 4; i++) mx = fmaxf(mx, sacc[tt][i]);
    if (q == 0)
      for (int i = 0; i < 4; i++) mx = fmaxf(mx, sacc[12][i]);
    mx = fmaxf(mx, __shfl_xor(mx, 16));
    mx = fmaxf(mx, __shfl_xor(mx, 32));
    const float CE = SCALE * 1.44269504f;
    float sm = 0.f;
    for (int tt = 0; tt < 12; tt++)
      for (int i = 0; i < 4; i++) {
        float e = __builtin_amdgcn_exp2f((sacc[tt][i] - mx) * CE);
        sacc[tt][i] = e; sm += e;
      }
    if (q == 0) {
      for (int i = 0; i < 4; i++) {
        float e = __builtin_amdgcn_exp2f((sacc[12][i] - mx) * CE);
        sacc[12][i] = e; sm += e;
      }
    } else {
      sacc[12] = (float4v){0.f, 0.f, 0.f, 0.f};
    }
    sm += __shfl_xor(sm, 16);
    sm += __shfl_xor(sm, 32);
    const float inv = 1.0f / sm;

    // P^T fragments: pfrag[t][j] = P^T[m = t*32 + q*8 + j][n], j = h4*4 + i
    // bias from saT[m][n]: scalar f32 loads, 16 lanes hit 16 consecutive n (coalesced)
    short8 pfrag[7];
    for (int t = 0; t < 7; t++) {
      short8 pf;
      for (int h4 = 0; h4 < 2; h4++) {
        int tt = 2 * t + h4;
        bool valid = (tt < 12) || (tt == 12 && q == 0);
        float a0 = 0.f, a1 = 0.f, a2 = 0.f, a3 = 0.f;
        if (valid) {
          const float* sp = saTh + (size_t)(t * 32 + q * 8 + h4 * 4) * SEQ + nql;
          a0 = sp[0]; a1 = sp[SEQ]; a2 = sp[2 * SEQ]; a3 = sp[3 * SEQ];
        }
        int src = valid ? tt : 13;
        float pv0 = valid ? (sacc[src][0] * inv + a0) : 0.f;
        float pv1 = valid ? (sacc[src][1] * inv + a1) : 0.f;
        float pv2 = valid ? (sacc[src][2] * inv + a2) : 0.f;
        float pv3 = valid ? (sacc[src][3] * inv + a3) : 0.f;
        pf[h4 * 4 + 0] = (short)f2bf(pv0);
        pf[h4 * 4 + 1] = (short)f2bf(pv1);
        pf[h4 * 4 + 2] = (short)f2bf(pv2);
        pf[h4 * 4 + 3] = (short)f2bf(pv3);
      }
      pfrag[t] = pf;
    }

    // O^T = V^T . P^T : A-frag = V^T rows (from LDS, two b64 reads), B-frag = pfrag
    for (int dt = 0; dt < 4; dt++) {
      float4v o = (float4v){0.f, 0.f, 0.f, 0.f};
      for (int t = 0; t < 7; t++) {
        const unsigned short* vp = &Vt[(dt * 16 + s) * WV + t * 32 + q * 8];
        short4v v0 = *(const short4v*)vp;
        short4v v1 = *(const short4v*)(vp + 4);
        short8 vf;
        vf[0] = v0[0]; vf[1] = v0[1]; vf[2] = v0[2]; vf[3] = v0[3];
        vf[4] = v1[0]; vf[5] = v1[1]; vf[6] = v1[2]; vf[7] = v1[3];
        o = __builtin_amdgcn_mfma_f32_16x16x32_bf16(vf, pfrag[t], o, 0, 0, 0);
      }
      // lane holds O^T[d = dt*16 + q*4 + r][n = nq]
      if (nq < 196) {
        ushort4v ov;
        ov.x = f2bf(o[0]); ov.y = f2bf(o[1]); ov.z = f2bf(o[2]); ov.w = f2bf(o[3]);
        *(ushort4v*)&outA[((size_t)b * SEQ + nq) * DIM + h * 64 + dt * 16 + q * 4] = ov;
      }
    }
  }
}

extern "C" void kernel_launch(void* const* d_in, const int* in_sizes, int n_in,
                              void* d_out, int out_size, void* d_ws, size_t ws_size,
                              hipStream_t stream) {
  const float* x        = (const float*)d_in[0];
  const float* Wqkv     = (const float*)d_in[1];
  const float* static_a = (const float*)d_in[2];
  const float* Wproj    = (const float*)d_in[3];
  const float* bproj    = (const float*)d_in[4];
  float* out = (float*)d_out;

  unsigned char* ws = (unsigned char*)d_ws;
  size_t off = 0;
  unsigned short* qkv_ws = (unsigned short*)(ws + off); off += (size_t)NTOK * QKVLD * 2;   // 57.8 MB
  unsigned short* xa_ws  = (unsigned short*)(ws + off); off += (size_t)NTOK * DIM * 2;     // x_bf16, reused as attn-out
  unsigned short* wqkvt  = (unsigned short*)(ws + off); off += (size_t)3 * DIM * DIM * 2;  // W_qkv^T bf16
  unsigned short* wprojt = (unsigned short*)(ws + off); off += (size_t)DIM * DIM * 2;      // W_proj^T bf16
  float* saT_ws          = (float*)(ws + off);          off += (size_t)HEADS * SEQ * SEQ * 4; // 1.84 MB

  cast_x_kernel<<<NTOK * DIM / 4 / 256, 256, 0, stream>>>(x, xa_ws);
  transpose_cast_kernel<<<dim3(3 * DIM / 32, DIM / 32), dim3(32, 8), 0, stream>>>(Wqkv, wqkvt, DIM, 3 * DIM);
  transpose_cast_kernel<<<dim3(DIM / 32, DIM / 32), dim3(32, 8), 0, stream>>>(Wproj, wprojt, DIM, DIM);
  transpose_sa_kernel<<<dim3(7, 7, HEADS), dim3(32, 8), 0, stream>>>(static_a, saT_ws);
  gemm256_kernel<0><<<dim3(3 * DIM / 256, NTOK / 256), 512, 0, stream>>>(xa_ws, wqkvt, nullptr, qkv_ws, nullptr);
  attn_kernel<<<BATCH * HEADS, 256, 0, stream>>>(qkv_ws, saT_ws, xa_ws);
  gemm256_kernel<1><<<dim3(DIM / 256, NTOK / 256), 512, 0, stream>>>(xa_ws, wprojt, bproj, nullptr, out);
}

// Round 3
// 241.301 us; speedup vs baseline: 1.0420x; 1.0059x over previous
//
#include <hip/hip_runtime.h>
#include <stdint.h>

#define DIM 768
#define HEADS 12
#define SEQ 196
#define BATCH 64
#define NTOK (BATCH*SEQ)   // 12544
#define QKVLD (3*DIM)      // 2304, row stride of qkv workspace
#define SCALE 0.125f       // 64^-0.5

using short8  = __attribute__((ext_vector_type(8))) short;
using short4v = __attribute__((ext_vector_type(4))) short;
using float4v = __attribute__((ext_vector_type(4))) float;
using ushort4v = __attribute__((ext_vector_type(4))) unsigned short;

static __device__ __forceinline__ unsigned short f2bf(float f) {
  union { float f; unsigned u; } v; v.f = f;
  unsigned u = v.u;
  u += 0x7fffu + ((u >> 16) & 1u);   // RNE
  return (unsigned short)(u >> 16);
}

#if defined(__has_builtin)
#if __has_builtin(__builtin_amdgcn_global_load_lds)
#define HAS_GLL 1
#endif
#endif

// Stage 16B/lane: global (per-lane ptr g) -> LDS (wave-uniform base l, lane*16B apart)
static __device__ __forceinline__ void gll16(const unsigned short* g, unsigned short* l) {
#ifdef HAS_GLL
  __builtin_amdgcn_global_load_lds(
      (const __attribute__((address_space(1))) void*)g,
      (__attribute__((address_space(3))) void*)l, 16, 0, 0);
#else
  const int lane = threadIdx.x & 63;
  *(short8*)(l + lane * 8) = *(const short8*)g;
#endif
}

// raw barrier (no vmcnt drain) with compiler memory-motion fences
static __device__ __forceinline__ void barx() {
  asm volatile("" ::: "memory");
  __builtin_amdgcn_s_barrier();
  asm volatile("" ::: "memory");
}
#define VMW8 asm volatile("s_waitcnt vmcnt(8)" ::: "memory")
#define VMW4 asm volatile("s_waitcnt vmcnt(4)" ::: "memory")
#define VMW0 asm volatile("s_waitcnt vmcnt(0)" ::: "memory")

// ---------------- pre-pass: cast x fp32 -> bf16 ----------------
__global__ __launch_bounds__(256) void cast_x_kernel(const float* __restrict__ in,
                                                     unsigned short* __restrict__ out) {
  int i = blockIdx.x * 256 + threadIdx.x;      // exactly NTOK*DIM/4 threads
  float4 v = ((const float4*)in)[i];
  ushort4v o;
  o.x = f2bf(v.x); o.y = f2bf(v.y); o.z = f2bf(v.z); o.w = f2bf(v.w);
  ((ushort4v*)out)[i] = o;
}

// ---------------- pre-pass: transpose + cast W [R][C] fp32 -> Wt [C][R] bf16 ----------------
__global__ __launch_bounds__(256) void transpose_cast_kernel(const float* __restrict__ in,
                                                             unsigned short* __restrict__ out,
                                                             int R, int C) {
  __shared__ float tile[32][33];
  int c0 = blockIdx.x * 32, r0 = blockIdx.y * 32;
  int tx = threadIdx.x, ty = threadIdx.y;      // (32,8)
  for (int i = 0; i < 32; i += 8)
    tile[ty + i][tx] = in[(size_t)(r0 + ty + i) * C + c0 + tx];
  __syncthreads();
  for (int i = 0; i < 32; i += 8)
    out[(size_t)(c0 + ty + i) * R + r0 + tx] = f2bf(tile[tx][ty + i]);
}

// ---------------- pre-pass: transpose static_a per head: saT[h][m][n] = sa[h][n][m] ----------------
__global__ __launch_bounds__(256) void transpose_sa_kernel(const float* __restrict__ in,
                                                           float* __restrict__ out) {
  __shared__ float tile[32][33];
  const int h = blockIdx.z;
  const int n0 = blockIdx.x * 32, m0 = blockIdx.y * 32;
  const int tx = threadIdx.x, ty = threadIdx.y;   // (32,8)
  const float* inh = in + (size_t)h * SEQ * SEQ;
  float* outh = out + (size_t)h * SEQ * SEQ;
  for (int i = 0; i < 32; i += 8)
    if (n0 + ty + i < SEQ && m0 + tx < SEQ)
      tile[ty + i][tx] = inh[(size_t)(n0 + ty + i) * SEQ + m0 + tx];
  __syncthreads();
  for (int i = 0; i < 32; i += 8)
    if (m0 + ty + i < SEQ && n0 + tx < SEQ)
      outh[(size_t)(m0 + ty + i) * SEQ + n0 + tx] = tile[tx][ty + i];
}

// ---------------- GEMM: C[M][N] = A[M][768] * Bt[N][768]^T ----------------
// 256x256 tile, BK=32, 8 waves (2Mx4N), 4-deep LDS pipeline, counted vmcnt,
// ONE barrier per K-tile, and REGISTER-PREFETCHED fragments: tile t's (bfr,afr)
// are read from LDS during tile t-1, so the MFMA cluster issues with no lgkm
// stall and the LDS pipe services tile t+1's reads WHILE the MFMA pipe drains.
// afr2 (A rows 4..7) is read at tile top and consumed by MFMA #17+ (~310 cyc
// later), also stall-free. vmcnt(4) before each barrier guarantees slot t+1
// globally landed before any wave prefetch-reads it next tile.
// Swizzle: chunk ^= (row>>1)&3 -> conflict-free (verified: BANK_CONFLICT=0).
// MODE 0: C^T-register formulation, bf16 out row-major [M][2304]
// MODE 1: fp32 out[m][768] + bias[n]
template <int MODE>
__global__ __launch_bounds__(512, 2) void gemm256_kernel(const unsigned short* __restrict__ A,
                                                         const unsigned short* __restrict__ Bt,
                                                         const float* __restrict__ bias,
                                                         unsigned short* __restrict__ outB,
                                                         float* __restrict__ outF) {
  constexpr int K = 768;
  constexpr int NT = 24;                               // K-tiles of 32
  __shared__ __align__(16) unsigned short Als[4][8192];   // [slot][256 rows][32 cols]
  __shared__ __align__(16) unsigned short Bls[4][8192];
  const int tid = threadIdx.x;
  const int wid = tid >> 6, lane = tid & 63;
  const int s = lane & 15, q = lane >> 4;
  const int wr = wid >> 2, wc = wid & 3;               // 2x4 wave grid, 128x64 per wave
  const int qx8 = ((q ^ ((s >> 1) & 3)) << 3);         // swizzled 16B slot for frag reads

  // XCD-aware bijective swizzle: contiguous id chunk per XCD -> panels L2-resident.
  const int nbx = gridDim.x;
  const int nb = gridDim.x * gridDim.y;
  int id = blockIdx.y * nbx + blockIdx.x;
  {
    int x = id & 7, lid = id >> 3;
    int per = nb >> 3, big = nb & 7;
    id = (x < big) ? x * (per + 1) + lid
                   : big * (per + 1) + (x - big) * per + lid;
  }
  const int m0 = (id / nbx) * 256;
  const int n0 = (id % nbx) * 256;

  float4v acc[8][4];
#pragma unroll
  for (int i = 0; i < 8; i++)
#pragma unroll
    for (int j = 0; j < 4; j++) acc[i][j] = (float4v){0.f, 0.f, 0.f, 0.f};

  // Staging: thread t covers 16B chunks t and 512+t (row +128). Linear LDS dest
  // (gll requirement); SOURCE column-chunk pre-permuted by the read involution.
  const int srow = tid >> 2;                             // 0..127
  const int scol8 = (((tid & 3) ^ ((srow >> 1) & 3)) << 3);
  const unsigned short* gA = A + (size_t)(m0 + srow) * K + scol8;
  const unsigned short* gB = Bt + (size_t)(n0 + srow) * K + scol8;
  unsigned short* lA0 = &Als[0][0] + wid * 512;
  unsigned short* lB0 = &Bls[0][0] + wid * 512;

  auto stage = [&](int t_) {
    const unsigned short* a = gA + t_ * 32;
    const unsigned short* b = gB + t_ * 32;
    unsigned short* la = lA0 + (t_ & 3) * 8192;
    unsigned short* lb = lB0 + (t_ & 3) * 8192;
    gll16(a, la); gll16(a + 128 * K, la + 4096);
    gll16(b, lb); gll16(b + 128 * K, lb + 4096);
  };

  // prologue: stage tiles 0,1,2; retire tiles 0 AND 1 (tile 1 is prefetch-read
  // during tile 0, so it must be globally landed before the loop starts).
  stage(0); stage(1); stage(2);
  VMW4;
  barx();

  const int laneA = (wr * 128 + s) * 32 + qx8;   // element offset of frag base
  const int laneB = (wc * 64 + s) * 32 + qx8;

  short8 bfrP[4], afrP[4], bfrQ[4], afrQ[4], afr2[4];
  {
    const unsigned short* As = &Als[0][0];
    const unsigned short* Bs = &Bls[0][0];
#pragma unroll
    for (int nj = 0; nj < 4; ++nj) bfrP[nj] = *(const short8*)&Bs[laneB + nj * 512];
#pragma unroll
    for (int mi = 0; mi < 4; ++mi) afrP[mi] = *(const short8*)&As[laneA + mi * 512];
  }

#define MFMA_CLUSTER(BFR, AFR, A2)                                                             \
  __builtin_amdgcn_s_setprio(1);                                                               \
  _Pragma("unroll")                                                                            \
  for (int mi = 0; mi < 4; ++mi)                                                               \
    _Pragma("unroll")                                                                          \
    for (int nj = 0; nj < 4; ++nj) {                                                           \
      if (MODE == 0)                                                                           \
        acc[mi][nj] = __builtin_amdgcn_mfma_f32_16x16x32_bf16(BFR[nj], AFR[mi], acc[mi][nj], 0, 0, 0); \
      else                                                                                     \
        acc[mi][nj] = __builtin_amdgcn_mfma_f32_16x16x32_bf16(AFR[mi], BFR[nj], acc[mi][nj], 0, 0, 0); \
    }                                                                                          \
  _Pragma("unroll")                                                                            \
  for (int mi = 0; mi < 4; ++mi)                                                               \
    _Pragma("unroll")                                                                          \
    for (int nj = 0; nj < 4; ++nj) {                                                           \
      if (MODE == 0)                                                                           \
        acc[mi + 4][nj] = __builtin_amdgcn_mfma_f32_16x16x32_bf16(BFR[nj], A2[mi], acc[mi + 4][nj], 0, 0, 0); \
      else                                                                                     \
        acc[mi + 4][nj] = __builtin_amdgcn_mfma_f32_16x16x32_bf16(A2[mi], BFR[nj], acc[mi + 4][nj], 0, 0, 0); \
    }                                                                                          \
  __builtin_amdgcn_s_setprio(0);

#pragma unroll 1
  for (int tt = 0; tt < NT; tt += 2) {
    // ---- even tile tt: cur frags in P; prefetch Q <- slot (tt+1)&3 ----
    {
      const unsigned short* Asc = &Als[0][0] + (tt & 3) * 8192;
#pragma unroll
      for (int mi = 0; mi < 4; ++mi) afr2[mi] = *(const short8*)&Asc[laneA + (mi + 4) * 512];
      const unsigned short* Asn = &Als[0][0] + ((tt + 1) & 3) * 8192;
      const unsigned short* Bsn = &Bls[0][0] + ((tt + 1) & 3) * 8192;
#pragma unroll
      for (int nj = 0; nj < 4; ++nj) bfrQ[nj] = *(const short8*)&Bsn[laneB + nj * 512];
#pragma unroll
      for (int mi = 0; mi < 4; ++mi) afrQ[mi] = *(const short8*)&Asn[laneA + mi * 512];
      if (tt <= NT - 4) stage(tt + 3);
      MFMA_CLUSTER(bfrP, afrP, afr2)
      if (tt <= NT - 4) { VMW4; } else { VMW0; }
      barx();
    }
    // ---- odd tile tt+1: cur frags in Q; prefetch P <- slot (tt+2)&3 ----
    {
      const unsigned short* Asc = &Als[0][0] + ((tt + 1) & 3) * 8192;
#pragma unroll
      for (int mi = 0; mi < 4; ++mi) afr2[mi] = *(const short8*)&Asc[laneA + (mi + 4) * 512];
      if (tt + 2 < NT) {
        const unsigned short* Asn = &Als[0][0] + ((tt + 2) & 3) * 8192;
        const unsigned short* Bsn = &Bls[0][0] + ((tt + 2) & 3) * 8192;
#pragma unroll
        for (int nj = 0; nj < 4; ++nj) bfrP[nj] = *(const short8*)&Bsn[laneB + nj * 512];
#pragma unroll
        for (int mi = 0; mi < 4; ++mi) afrP[mi] = *(const short8*)&Asn[laneA + mi * 512];
      }
      if (tt + 1 <= NT - 4) stage(tt + 4);
      MFMA_CLUSTER(bfrQ, afrQ, afr2)
      if (tt + 1 <= NT - 4) { VMW4; } else { VMW0; }
      barx();
    }
  }
#undef MFMA_CLUSTER

  if (MODE == 0) {
    // lane (s,q) acc[mi][nj][r] = C[m0+wr*128+mi*16+s][n0+wc*64+nj*16+q*4+r]
#pragma unroll
    for (int mi = 0; mi < 8; ++mi) {
      size_t mrow = (size_t)(m0 + wr * 128 + mi * 16 + s) * QKVLD;
#pragma unroll
      for (int nj = 0; nj < 4; ++nj) {
        int n = n0 + wc * 64 + nj * 16 + q * 4;
        ushort4v ov;
        ov.x = f2bf(acc[mi][nj][0]); ov.y = f2bf(acc[mi][nj][1]);
        ov.z = f2bf(acc[mi][nj][2]); ov.w = f2bf(acc[mi][nj][3]);
        *(ushort4v*)&outB[mrow + n] = ov;
      }
    }
  } else {
    // lane (s,q) acc[mi][nj][r] = C[m0+wr*128+mi*16+q*4+r][n0+wc*64+nj*16+s]
#pragma unroll
    for (int mi = 0; mi < 8; ++mi) {
      int mbase = m0 + wr * 128 + mi * 16 + q * 4;
#pragma unroll
      for (int nj = 0; nj < 4; ++nj) {
        int ng = n0 + wc * 64 + nj * 16 + s;
        float bv = bias[ng];
#pragma unroll
        for (int r = 0; r < 4; ++r)
          outF[(size_t)(mbase + r) * 768 + ng] = acc[mi][nj][r] + bv;
      }
    }
  }
}

// ---------------- attention: one block per (b,h), S^T formulation ----------------
// qkv workspace is [NTOK][2304] row-major. K is staged into LDS once (coalesced
// 128B global reads), XOR-swizzled so the permuted-row fragment reads are
// conflict-free-ish; static_a is pre-transposed so bias loads are lane-coalesced.
__global__ __launch_bounds__(256) void attn_kernel(const unsigned short* __restrict__ qkv,
                                                   const float* __restrict__ saT,
                                                   unsigned short* __restrict__ outA) {
  constexpr int WV = 228;   // stride: 114 dwords == 18 mod 32 -> b64 frag reads conflict-free
  __shared__ __align__(16) unsigned short Kl[196 * 64];  // K rows, chunk-swizzled
  __shared__ __align__(16) unsigned short Vt[64 * WV];   // V^T [d][m], m zero-padded to 224
  const int tid = threadIdx.x, wid = tid >> 6, lane = tid & 63;
  const int s = lane & 15, q = lane >> 4;
  const int bh = blockIdx.x;
  const int b = bh / 12, h = bh % 12;
  const unsigned short* Qb = qkv + (size_t)b * SEQ * QKVLD + h * 64;
  const unsigned short* Kb = Qb + 768;
  const unsigned short* Vb = Qb + 1536;

  // stage K: row r, chunk c (16B); LDS chunk = c ^ gK(r); 8 lanes/row -> 128B coalesced
  {
    const int r0 = tid >> 3, c = tid & 7;
    for (int p = 0; p < 7; ++p) {
      int r = p * 32 + r0;
      if (r < 196) {
        short8 v = *(const short8*)&Kb[(size_t)r * QKVLD + c * 8];
        int gk = ((r >> 3) & 3) ^ ((r & 1) << 2);
        *(short8*)&Kl[r * 64 + ((c ^ gk) << 3)] = v;
      }
    }
  }
  // stage V^T: thread covers m = mb*64 + (tid&63), d = d0..d0+15
  {
    const int ms = tid & 63;
    const int d0 = (tid >> 6) * 16;
    for (int mb = 0; mb < 4; ++mb) {
      int m = mb * 64 + ms;
      if (m < 224) {
        if (m < 196) {
          short8 v0 = *(const short8*)&Vb[(size_t)m * QKVLD + d0];
          short8 v1 = *(const short8*)&Vb[(size_t)m * QKVLD + d0 + 8];
          for (int j = 0; j < 8; j++) Vt[(d0 + j) * WV + m] = (unsigned short)v0[j];
          for (int j = 0; j < 8; j++) Vt[(d0 + 8 + j) * WV + m] = (unsigned short)v1[j];
        } else {
          for (int j = 0; j < 16; j++) Vt[(d0 + j) * WV + m] = 0;
        }
      }
    }
  }
  __syncthreads();

  const int pmbase = (s >> 2) * 8 + (s & 3);   // permuted K-row base for A-frag row s
  const float* saTh = saT + (size_t)h * SEQ * SEQ;

  for (int qt = wid; qt < 13; qt += 4) {
    const int n0 = qt * 16;
    const int nq = n0 + s;
    const int nql = nq > 195 ? 195 : nq;
    short8 qf0 = *(const short8*)&Qb[(size_t)nql * QKVLD + q * 8];
    short8 qf1 = *(const short8*)&Qb[(size_t)nql * QKVLD + 32 + q * 8];

    // S^T tiles: tt = 0..12 (tt = 2t + h4; tile (t=6,h4=1) is entirely m>=196 -> skipped)
    float4v sacc[14];
    for (int tt = 0; tt < 13; tt++) {
      int t = tt >> 1, h4 = tt & 1;
      int m = t * 32 + h4 * 4 + pmbase;
      if (m > 195) m = 195;                       // garbage rows, masked later
      int gk = ((m >> 3) & 3) ^ ((m & 1) << 2);
      short8 kf0 = *(const short8*)&Kl[m * 64 + ((q ^ gk) << 3)];
      short8 kf1 = *(const short8*)&Kl[m * 64 + (((4 + q) ^ gk) << 3)];
      float4v z = (float4v){0.f, 0.f, 0.f, 0.f};
      z = __builtin_amdgcn_mfma_f32_16x16x32_bf16(kf0, qf0, z, 0, 0, 0);
      z = __builtin_amdgcn_mfma_f32_16x16x32_bf16(kf1, qf1, z, 0, 0, 0);
      sacc[tt] = z;
    }
    sacc[13] = (float4v){0.f, 0.f, 0.f, 0.f};

    // column softmax: lane owns column n. Valid m: tt<12 all; tt==12 only q==0.
    float mx = -3.0e38f;
    for (int tt = 0; tt < 12; tt++)
      for (int i = 0; i < 4; i++) mx = fmaxf(mx, sacc[tt][i]);
    if (q == 0)
      for (int i = 0; i < 4; i++) mx = fmaxf(mx, sacc[12][i]);
    mx = fmaxf(mx, __shfl_xor(mx, 16));
    mx = fmaxf(mx, __shfl_xor(mx, 32));
    const float CE = SCALE * 1.44269504f;
    float sm = 0.f;
    for (int tt = 0; tt < 12; tt++)
      for (int i = 0; i < 4; i++) {
        float e = __builtin_amdgcn_exp2f((sacc[tt][i] - mx) * CE);
        sacc[tt][i] = e; sm += e;
      }
    if (q == 0) {
      for (int i = 0; i < 4; i++) {
        float e = __builtin_amdgcn_exp2f((sacc[12][i] - mx) * CE);
        sacc[12][i] = e; sm += e;
      }
    } else {
      sacc[12] = (float4v){0.f, 0.f, 0.f, 0.f};
    }
    sm += __shfl_xor(sm, 16);
    sm += __shfl_xor(sm, 32);
    const float inv = 1.0f / sm;

    // P^T fragments: pfrag[t][j] = P^T[m = t*32 + q*8 + j][n], j = h4*4 + i
    // bias from saT[m][n]: scalar f32 loads, 16 lanes hit 16 consecutive n (coalesced)
    short8 pfrag[7];
    for (int t = 0; t < 7; t++) {
      short8 pf;
      for (int h4 = 0; h4 < 2; h4++) {
        int tt = 2 * t + h4;
        bool valid = (tt < 12) || (tt == 12 && q == 0);
        float a0 = 0.f, a1 = 0.f, a2 = 0.f, a3 = 0.f;
        if (valid) {
          const float* sp = saTh + (size_t)(t * 32 + q * 8 + h4 * 4) * SEQ + nql;
          a0 = sp[0]; a1 = sp[SEQ]; a2 = sp[2 * SEQ]; a3 = sp[3 * SEQ];
        }
        int src = valid ? tt : 13;
        float pv0 = valid ? (sacc[src][0] * inv + a0) : 0.f;
        float pv1 = valid ? (sacc[src][1] * inv + a1) : 0.f;
        float pv2 = valid ? (sacc[src][2] * inv + a2) : 0.f;
        float pv3 = valid ? (sacc[src][3] * inv + a3) : 0.f;
        pf[h4 * 4 + 0] = (short)f2bf(pv0);
        pf[h4 * 4 + 1] = (short)f2bf(pv1);
        pf[h4 * 4 + 2] = (short)f2bf(pv2);
        pf[h4 * 4 + 3] = (short)f2bf(pv3);
      }
      pfrag[t] = pf;
    }

    // O^T = V^T . P^T : A-frag = V^T rows (from LDS, two b64 reads), B-frag = pfrag
    for (int dt = 0; dt < 4; dt++) {
      float4v o = (float4v){0.f, 0.f, 0.f, 0.f};
      for (int t = 0; t < 7; t++) {
        const unsigned short* vp = &Vt[(dt * 16 + s) * WV + t * 32 + q * 8];
        short4v v0 = *(const short4v*)vp;
        short4v v1 = *(const short4v*)(vp + 4);
        short8 vf;
        vf[0] = v0[0]; vf[1] = v0[1]; vf[2] = v0[2]; vf[3] = v0[3];
        vf[4] = v1[0]; vf[5] = v1[1]; vf[6] = v1[2]; vf[7] = v1[3];
        o = __builtin_amdgcn_mfma_f32_16x16x32_bf16(vf, pfrag[t], o, 0, 0, 0);
      }
      // lane holds O^T[d = dt*16 + q*4 + r][n = nq]
      if (nq < 196) {
        ushort4v ov;
        ov.x = f2bf(o[0]); ov.y = f2bf(o[1]); ov.z = f2bf(o[2]); ov.w = f2bf(o[3]);
        *(ushort4v*)&outA[((size_t)b * SEQ + nq) * DIM + h * 64 + dt * 16 + q * 4] = ov;
      }
    }
  }
}

extern "C" void kernel_launch(void* const* d_in, const int* in_sizes, int n_in,
                              void* d_out, int out_size, void* d_ws, size_t ws_size,
                              hipStream_t stream) {
  const float* x        = (const float*)d_in[0];
  const float* Wqkv     = (const float*)d_in[1];
  const float* static_a = (const float*)d_in[2];
  const float* Wproj    = (const float*)d_in[3];
  const float* bproj    = (const float*)d_in[4];
  float* out = (float*)d_out;

  unsigned char* ws = (unsigned char*)d_ws;
  size_t off = 0;
  unsigned short* qkv_ws = (unsigned short*)(ws + off); off += (size_t)NTOK * QKVLD * 2;   // 57.8 MB
  unsigned short* xa_ws  = (unsigned short*)(ws + off); off += (size_t)NTOK * DIM * 2;     // x_bf16, reused as attn-out
  unsigned short* wqkvt  = (unsigned short*)(ws + off); off += (size_t)3 * DIM * DIM * 2;  // W_qkv^T bf16
  unsigned short* wprojt = (unsigned short*)(ws + off); off += (size_t)DIM * DIM * 2;      // W_proj^T bf16
  float* saT_ws          = (float*)(ws + off);          off += (size_t)HEADS * SEQ * SEQ * 4; // 1.84 MB

  cast_x_kernel<<<NTOK * DIM / 4 / 256, 256, 0, stream>>>(x, xa_ws);
  transpose_cast_kernel<<<dim3(3 * DIM / 32, DIM / 32), dim3(32, 8), 0, stream>>>(Wqkv, wqkvt, DIM, 3 * DIM);
  transpose_cast_kernel<<<dim3(DIM / 32, DIM / 32), dim3(32, 8), 0, stream>>>(Wproj, wprojt, DIM, DIM);
  transpose_sa_kernel<<<dim3(7, 7, HEADS), dim3(32, 8), 0, stream>>>(static_a, saT_ws);
  gemm256_kernel<0><<<dim3(3 * DIM / 256, NTOK / 256), 512, 0, stream>>>(xa_ws, wqkvt, nullptr, qkv_ws, nullptr);
  attn_kernel<<<BATCH * HEADS, 256, 0, stream>>>(qkv_ws, saT_ws, xa_ws);
  gemm256_kernel<1><<<dim3(DIM / 256, NTOK / 256), 512, 0, stream>>>(xa_ws, wprojt, bproj, nullptr, out);
}